// Round 4
// baseline (417.828 us; speedup 1.0000x reference)
//
#include <hip/hip_runtime.h>
#include <hip/hip_bf16.h>

#define N1 8192
#define N2 8192
#define CDIM 128
#define HC 60
#define WC 80
#define HIMG 480
#define WIMG 640
#define INV_DENOM (1.0f / (8192.0f * 256.0f))

using bf16x8 = __attribute__((ext_vector_type(8))) short;
using f32x4  = __attribute__((ext_vector_type(4))) float;
using u32x8  = __attribute__((ext_vector_type(8))) unsigned;

__device__ __forceinline__ ushort f2bf(float f) {
    union { float f; unsigned u; } x; x.f = f;
    unsigned u = x.u;
    unsigned r = (u + 0x7FFFu + ((u >> 16) & 1u)) >> 16;
    return (ushort)r;
}
__device__ __forceinline__ float bf2f(unsigned bits) {
    union { unsigned u; float f; } x; x.u = bits << 16; return x.f;
}

// ---------- fp32 -> bf16 convert (vectorized) ----------
__global__ void cvt_kernel(const float* __restrict__ in, ushort* __restrict__ out, int n4) {
    int i = blockIdx.x * blockDim.x + threadIdx.x;
    if (i < n4) {
        float4 v = ((const float4*)in)[i];
        ushort4 o;
        o.x = f2bf(v.x); o.y = f2bf(v.y); o.z = f2bf(v.z); o.w = f2bf(v.w);
        ((ushort4*)out)[i] = o;
    }
}

// ---------- positive term ----------
__global__ void pos_kernel(const float* __restrict__ wkp1,
                           const float* __restrict__ kp1d,
                           const float* __restrict__ desc2,
                           float* __restrict__ out) {
    const int i = blockIdx.x;
    const int c = threadIdx.x;            // 128 threads = 2 waves
    float y = wkp1[2 * i], x = wkp1[2 * i + 1];
    float py = fminf(fmaxf(y / (float)(HIMG - 1) * (float)(HC - 1), 0.0f), (float)(HC - 1));
    float px = fminf(fmaxf(x / (float)(WIMG - 1) * (float)(WC - 1), 0.0f), (float)(WC - 1));
    int y0 = min(max((int)floorf(py), 0), HC - 2);
    int x0 = min(max((int)floorf(px), 0), WC - 2);
    float wy = py - (float)y0;
    float wx = px - (float)x0;
    const float* d = desc2 + (size_t)c * (HC * WC) + y0 * WC + x0;
    float v00 = d[0], v01 = d[1], v10 = d[WC], v11 = d[WC + 1];
    float v = v00 * (1.0f - wy) * (1.0f - wx) + v01 * (1.0f - wy) * wx
            + v10 * wy * (1.0f - wx) + v11 * wy * wx;
    float a = kp1d[(size_t)i * CDIM + c];
    float s2 = v * v, sav = a * v;
    #pragma unroll
    for (int off = 32; off >= 1; off >>= 1) {
        s2  += __shfl_down(s2, off);
        sav += __shfl_down(sav, off);
    }
    __shared__ float p2[2], pav[2];
    int wave = threadIdx.x >> 6, lane = threadIdx.x & 63;
    if (lane == 0) { p2[wave] = s2; pav[wave] = sav; }
    __syncthreads();
    if (threadIdx.x == 0) {
        float nrm = sqrtf(p2[0] + p2[1]);
        float pd = (pav[0] + pav[1]) / fmaxf(nrm, 1e-12f);
        float l = fmaxf(1.0f - pd, 0.0f) * (256.0f / 3.0f);
        atomicAdd(out, l * INV_DENOM);
    }
}

// ---------- masked GEMM -> bf16 dots ----------
__global__ __launch_bounds__(256, 2)
void gemm_kernel(const ushort* __restrict__ A, const ushort* __restrict__ B,
                 const float* __restrict__ wkp1, const float* __restrict__ kp2,
                 ushort* __restrict__ dots, int m_off) {
    const int n0 = blockIdx.x * 128;
    const int m0 = m_off + blockIdx.y * 128;
    const int lane = threadIdx.x & 63;
    const int wave = threadIdx.x >> 6;
    const int wm = wave >> 1, wn = wave & 1;
    const int lrow = lane & 15, quad = lane >> 4;

    f32x4 acc[4][4];
    #pragma unroll
    for (int i = 0; i < 4; i++)
        #pragma unroll
        for (int j = 0; j < 4; j++) acc[i][j] = (f32x4){0.f, 0.f, 0.f, 0.f};

    const int mbase = m0 + wm * 64 + lrow;
    const int nbase = n0 + wn * 64 + lrow;
    #pragma unroll
    for (int kit = 0; kit < 4; kit++) {
        const int kk = kit * 32 + quad * 8;
        bf16x8 af[4], bfr[4];
        #pragma unroll
        for (int t = 0; t < 4; t++) {
            af[t]  = *(const bf16x8*)(A + (size_t)(mbase + t * 16) * CDIM + kk);
            bfr[t] = *(const bf16x8*)(B + (size_t)(nbase + t * 16) * CDIM + kk);
        }
        #pragma unroll
        for (int mt = 0; mt < 4; mt++)
            #pragma unroll
            for (int nt = 0; nt < 4; nt++)
                acc[mt][nt] = __builtin_amdgcn_mfma_f32_16x16x32_bf16(
                    af[mt], bfr[nt], acc[mt][nt], 0, 0, 0);
    }

    const float thr = 2.0f * sqrtf(32.0f) + 0.1f;
    const float thr2 = thr * thr;
    #pragma unroll
    for (int nt = 0; nt < 4; nt++) {
        int j = n0 + wn * 64 + nt * 16 + lrow;       // C/D: col = lane&15
        float ky = kp2[2 * j], kx = kp2[2 * j + 1];
        #pragma unroll
        for (int mt = 0; mt < 4; mt++) {
            #pragma unroll
            for (int r = 0; r < 4; r++) {
                int i = m0 + wm * 64 + mt * 16 + quad * 4 + r;  // row = (lane>>4)*4 + reg
                float wy = wkp1[2 * i], wx = wkp1[2 * i + 1];
                float dy = wy - ky, dx = wx - kx;
                float v = acc[mt][nt][r];
                if (dy * dy + dx * dx <= thr2) v -= 5.0f;
                dots[(size_t)(i - m_off) * N2 + j] = f2bf(v);
            }
        }
    }
}

// ---------- per-row top-256 hinge sum (integer-key bisection) ----------
// __launch_bounds__(256, 4): explicit waves/EU target -> VGPR budget 128.
// Without it the backend's occupancy heuristic throttled this kernel to 32
// VGPRs and spilled the key array to scratch (L2-resident, invisible in
// FETCH_SIZE) -- that was the 134 us. Keys live in four named u32x8 tuples.
__global__ __launch_bounds__(256, 4)
void select_kernel(const ushort* __restrict__ dots, float* __restrict__ out) {
    const int row = blockIdx.x;
    const int t = threadIdx.x;
    const int lane = t & 63, wave = t >> 6;
    const uint4* rp4 = (const uint4*)(dots + (size_t)row * N2);  // 8 bf16 per uint4

    u32x8 k0, k1, k2, k3;
    {
        uint4 w;
        unsigned kk;
#define LOADQ(vec, q)                                                     \
        w = rp4[(q) * 256 + t];                                           \
        kk = w.x ^ 0x80008000u ^ (((w.x >> 15) & 0x00010001u) * 0x7FFFu); \
        vec[0] = kk & 0xFFFFu; vec[1] = kk >> 16;                         \
        kk = w.y ^ 0x80008000u ^ (((w.y >> 15) & 0x00010001u) * 0x7FFFu); \
        vec[2] = kk & 0xFFFFu; vec[3] = kk >> 16;                         \
        kk = w.z ^ 0x80008000u ^ (((w.z >> 15) & 0x00010001u) * 0x7FFFu); \
        vec[4] = kk & 0xFFFFu; vec[5] = kk >> 16;                         \
        kk = w.w ^ 0x80008000u ^ (((w.w >> 15) & 0x00010001u) * 0x7FFFu); \
        vec[6] = kk & 0xFFFFu; vec[7] = kk >> 16;
        LOADQ(k0, 0)
        LOADQ(k1, 1)
        LOADQ(k2, 2)
        LOADQ(k3, 3)
#undef LOADQ
    }

    __shared__ int s_cnt[2][4];
    int lo = -1, hi = 65535;   // invariant: cnt(>lo) >= 256, cnt(>hi) <= 255
    #pragma unroll 1
    for (int it = 0; it < 16; it++) {
        unsigned mid = (unsigned)((lo + hi) >> 1);
        int c = 0;
        #pragma unroll
        for (int i = 0; i < 8; i++) c += (int)__popcll(__ballot(k0[i] > mid));
        #pragma unroll
        for (int i = 0; i < 8; i++) c += (int)__popcll(__ballot(k1[i] > mid));
        #pragma unroll
        for (int i = 0; i < 8; i++) c += (int)__popcll(__ballot(k2[i] > mid));
        #pragma unroll
        for (int i = 0; i < 8; i++) c += (int)__popcll(__ballot(k3[i] > mid));
        if (lane == 0) s_cnt[it & 1][wave] = c;
        __syncthreads();   // double buffer: next iter writes the other slot
        int total = s_cnt[it & 1][0] + s_cnt[it & 1][1]
                  + s_cnt[it & 1][2] + s_cnt[it & 1][3];
        if (total >= 256) lo = (int)mid; else hi = (int)mid;
    }
    const unsigned kt = (unsigned)hi;           // key of 256th-largest (attained)
    unsigned bt = kt ^ ((kt & 0x8000u) ? 0x8000u : 0xFFFFu);
    const float vt = bf2f(bt);

    float s = 0.0f; int cgt = 0;
#define EPI(vec)                                                          \
    _Pragma("unroll")                                                     \
    for (int i = 0; i < 8; i++) {                                         \
        cgt += (int)__popcll(__ballot(vec[i] > kt));                      \
        if (vec[i] > kt) {                                                \
            unsigned b = vec[i] ^ ((vec[i] & 0x8000u) ? 0x8000u : 0xFFFFu); \
            s += fmaxf(bf2f(b) - 0.2f, 0.0f);                             \
        }                                                                 \
    }
    EPI(k0) EPI(k1) EPI(k2) EPI(k3)
#undef EPI
    #pragma unroll
    for (int off = 32; off >= 1; off >>= 1) s += __shfl_down(s, off);
    __shared__ float s_s[4];
    __shared__ int s_c[4];
    if (lane == 0) { s_s[wave] = s; s_c[wave] = cgt; }
    __syncthreads();
    if (t == 0) {
        float st = s_s[0] + s_s[1] + s_s[2] + s_s[3];
        int ct = s_c[0] + s_c[1] + s_c[2] + s_c[3];
        float S = st + (float)(256 - ct) * fmaxf(vt - 0.2f, 0.0f);
        atomicAdd(out, S * INV_DENOM);
    }
}

extern "C" void kernel_launch(void* const* d_in, const int* in_sizes, int n_in,
                              void* d_out, int out_size, void* d_ws, size_t ws_size,
                              hipStream_t stream) {
    const float* wkp1  = (const float*)d_in[1];
    const float* kp2   = (const float*)d_in[2];
    const float* kp1d  = (const float*)d_in[3];
    const float* kp2d  = (const float*)d_in[4];
    const float* desc2 = (const float*)d_in[5];
    float* out = (float*)d_out;

    ushort* Abf = (ushort*)d_ws;                 // 2 MB
    ushort* Bbf = Abf + (size_t)N1 * CDIM;       // 2 MB
    ushort* dots = Bbf + (size_t)N2 * CDIM;      // remainder: desc_dot chunks (bf16)

    size_t desc_bytes = (size_t)(N1 + N2) * CDIM * sizeof(ushort);
    size_t avail = (ws_size > desc_bytes) ? (ws_size - desc_bytes) : 0;
    long rows_chunk = (long)(avail / ((size_t)N2 * sizeof(ushort)));
    rows_chunk = (rows_chunk / 128) * 128;
    if (rows_chunk > N1) rows_chunk = N1;
    if (rows_chunk < 128) rows_chunk = 128;      // requires ws >= ~6 MB

    hipMemsetAsync(d_out, 0, sizeof(float), stream);

    int n4 = N1 * CDIM / 4;
    cvt_kernel<<<(n4 + 255) / 256, 256, 0, stream>>>(kp1d, Abf, n4);
    cvt_kernel<<<(n4 + 255) / 256, 256, 0, stream>>>(kp2d, Bbf, n4);

    pos_kernel<<<N1, 128, 0, stream>>>(wkp1, kp1d, desc2, out);

    for (int r0 = 0; r0 < N1; r0 += (int)rows_chunk) {
        int rows = (int)((N1 - r0 < rows_chunk) ? (N1 - r0) : rows_chunk);
        dim3 grid(N2 / 128, rows / 128);
        gemm_kernel<<<grid, 256, 0, stream>>>(Abf, Bbf, wkp1, kp2, dots, r0);
        select_kernel<<<rows, 256, 0, stream>>>(dots, out);
    }
}

// Round 5
// 413.348 us; speedup vs baseline: 1.0108x; 1.0108x over previous
//
#include <hip/hip_runtime.h>
#include <hip/hip_bf16.h>

#define N1 8192
#define N2 8192
#define CDIM 128
#define HC 60
#define WC 80
#define HIMG 480
#define WIMG 640
#define INV_DENOM (1.0f / (8192.0f * 256.0f))

using bf16x8 = __attribute__((ext_vector_type(8))) short;
using f32x4  = __attribute__((ext_vector_type(4))) float;

__device__ __forceinline__ ushort f2bf(float f) {
    union { float f; unsigned u; } x; x.f = f;
    unsigned u = x.u;
    unsigned r = (u + 0x7FFFu + ((u >> 16) & 1u)) >> 16;
    return (ushort)r;
}
__device__ __forceinline__ float bf2f(unsigned bits) {
    union { unsigned u; float f; } x; x.u = bits << 16; return x.f;
}

// ---------- fp32 -> bf16 convert (vectorized) ----------
__global__ void cvt_kernel(const float* __restrict__ in, ushort* __restrict__ out, int n4) {
    int i = blockIdx.x * blockDim.x + threadIdx.x;
    if (i < n4) {
        float4 v = ((const float4*)in)[i];
        ushort4 o;
        o.x = f2bf(v.x); o.y = f2bf(v.y); o.z = f2bf(v.z); o.w = f2bf(v.w);
        ((ushort4*)out)[i] = o;
    }
}

// ---------- positive term ----------
__global__ void pos_kernel(const float* __restrict__ wkp1,
                           const float* __restrict__ kp1d,
                           const float* __restrict__ desc2,
                           float* __restrict__ out) {
    const int i = blockIdx.x;
    const int c = threadIdx.x;            // 128 threads = 2 waves
    float y = wkp1[2 * i], x = wkp1[2 * i + 1];
    float py = fminf(fmaxf(y / (float)(HIMG - 1) * (float)(HC - 1), 0.0f), (float)(HC - 1));
    float px = fminf(fmaxf(x / (float)(WIMG - 1) * (float)(WC - 1), 0.0f), (float)(WC - 1));
    int y0 = min(max((int)floorf(py), 0), HC - 2);
    int x0 = min(max((int)floorf(px), 0), WC - 2);
    float wy = py - (float)y0;
    float wx = px - (float)x0;
    const float* d = desc2 + (size_t)c * (HC * WC) + y0 * WC + x0;
    float v00 = d[0], v01 = d[1], v10 = d[WC], v11 = d[WC + 1];
    float v = v00 * (1.0f - wy) * (1.0f - wx) + v01 * (1.0f - wy) * wx
            + v10 * wy * (1.0f - wx) + v11 * wy * wx;
    float a = kp1d[(size_t)i * CDIM + c];
    float s2 = v * v, sav = a * v;
    #pragma unroll
    for (int off = 32; off >= 1; off >>= 1) {
        s2  += __shfl_down(s2, off);
        sav += __shfl_down(sav, off);
    }
    __shared__ float p2[2], pav[2];
    int wave = threadIdx.x >> 6, lane = threadIdx.x & 63;
    if (lane == 0) { p2[wave] = s2; pav[wave] = sav; }
    __syncthreads();
    if (threadIdx.x == 0) {
        float nrm = sqrtf(p2[0] + p2[1]);
        float pd = (pav[0] + pav[1]) / fmaxf(nrm, 1e-12f);
        float l = fmaxf(1.0f - pd, 0.0f) * (256.0f / 3.0f);
        atomicAdd(out, l * INV_DENOM);
    }
}

// ---------- masked GEMM -> bf16 dots ----------
__global__ __launch_bounds__(256, 2)
void gemm_kernel(const ushort* __restrict__ A, const ushort* __restrict__ B,
                 const float* __restrict__ wkp1, const float* __restrict__ kp2,
                 ushort* __restrict__ dots, int m_off) {
    const int n0 = blockIdx.x * 128;
    const int m0 = m_off + blockIdx.y * 128;
    const int lane = threadIdx.x & 63;
    const int wave = threadIdx.x >> 6;
    const int wm = wave >> 1, wn = wave & 1;
    const int lrow = lane & 15, quad = lane >> 4;

    f32x4 acc[4][4];
    #pragma unroll
    for (int i = 0; i < 4; i++)
        #pragma unroll
        for (int j = 0; j < 4; j++) acc[i][j] = (f32x4){0.f, 0.f, 0.f, 0.f};

    const int mbase = m0 + wm * 64 + lrow;
    const int nbase = n0 + wn * 64 + lrow;
    #pragma unroll
    for (int kit = 0; kit < 4; kit++) {
        const int kk = kit * 32 + quad * 8;
        bf16x8 af[4], bfr[4];
        #pragma unroll
        for (int t = 0; t < 4; t++) {
            af[t]  = *(const bf16x8*)(A + (size_t)(mbase + t * 16) * CDIM + kk);
            bfr[t] = *(const bf16x8*)(B + (size_t)(nbase + t * 16) * CDIM + kk);
        }
        #pragma unroll
        for (int mt = 0; mt < 4; mt++)
            #pragma unroll
            for (int nt = 0; nt < 4; nt++)
                acc[mt][nt] = __builtin_amdgcn_mfma_f32_16x16x32_bf16(
                    af[mt], bfr[nt], acc[mt][nt], 0, 0, 0);
    }

    const float thr = 2.0f * sqrtf(32.0f) + 0.1f;
    const float thr2 = thr * thr;
    #pragma unroll
    for (int nt = 0; nt < 4; nt++) {
        int j = n0 + wn * 64 + nt * 16 + lrow;       // C/D: col = lane&15
        float ky = kp2[2 * j], kx = kp2[2 * j + 1];
        #pragma unroll
        for (int mt = 0; mt < 4; mt++) {
            #pragma unroll
            for (int r = 0; r < 4; r++) {
                int i = m0 + wm * 64 + mt * 16 + quad * 4 + r;  // row = (lane>>4)*4 + reg
                float wy = wkp1[2 * i], wx = wkp1[2 * i + 1];
                float dy = wy - ky, dx = wx - kx;
                float v = acc[mt][nt][r];
                if (dy * dy + dx * dx <= thr2) v -= 5.0f;
                dots[(size_t)(i - m_off) * N2 + j] = f2bf(v);
            }
        }
    }
}

// ---------- per-row top-256 hinge sum (two-level histogram select) ----------
// Pass 1: 256-bin linear-value histogram (wave-privatized LDS atomics).
// Wave-0 shuffle suffix-scan -> boundary bin b, rank r within it.
// Pass 2: L2-hot re-read; bins>b accumulate relu(v-0.2); bin==b keys
// compacted to an LDS list (capacity 8192 = always safe).
// Wave-0 16-step key bisection over the list -> exact r-th largest + ties.
// No large register arrays -> immune to the remat/spill pathology of R2-R4.
__global__ __launch_bounds__(256)
void select_kernel(const ushort* __restrict__ dots, float* __restrict__ out) {
    const int row = blockIdx.x;
    const int t = threadIdx.x;
    const int lane = t & 63, wave = t >> 6;

    __shared__ unsigned hcnt[4][256];
    __shared__ ushort list[8192];
    __shared__ int ctrl[4];        // [0]=list count, [1]=b, [2]=r
    __shared__ float s_s[4];

    for (int i = t; i < 1024; i += 256) ((unsigned*)hcnt)[i] = 0u;
    if (t < 4) { ctrl[t] = 0; s_s[t] = 0.f; }
    __syncthreads();

    const uint4* rp4 = (const uint4*)(dots + (size_t)row * N2);  // 8 bf16 per uint4

    // ---- pass 1: histogram. bin = clamp(floor(v*2)+128, 0, 255): monotone,
    // contiguous value ranges, width 0.5 over [-64,64) (tails clamped).
    #pragma unroll
    for (int q = 0; q < 4; q++) {
        uint4 w = rp4[q * 256 + t];
        unsigned wd[4] = {w.x, w.y, w.z, w.w};
        #pragma unroll
        for (int u = 0; u < 4; u++) {
            unsigned x = wd[u];
            float v0 = bf2f(x & 0xFFFFu);
            float v1 = bf2f(x >> 16);
            int b0 = min(255, max(0, (int)floorf(v0 * 2.0f) + 128));
            int b1 = min(255, max(0, (int)floorf(v1 * 2.0f) + 128));
            atomicAdd(&hcnt[wave][b0], 1u);
            atomicAdd(&hcnt[wave][b1], 1u);
        }
    }
    __syncthreads();

    // ---- wave 0: suffix scan of 256 bins (4 bins/lane), find b and r.
    // Sinc(i) = count of elements in bins >= i (non-increasing, Sinc(0)=8192).
    // b = unique bin with Sinc(b) >= 256 and Sinc(b+1) < 256; r = 256 - Sinc(b+1).
    if (wave == 0) {
        int c0 = hcnt[0][4*lane+0] + hcnt[1][4*lane+0] + hcnt[2][4*lane+0] + hcnt[3][4*lane+0];
        int c1 = hcnt[0][4*lane+1] + hcnt[1][4*lane+1] + hcnt[2][4*lane+1] + hcnt[3][4*lane+1];
        int c2 = hcnt[0][4*lane+2] + hcnt[1][4*lane+2] + hcnt[2][4*lane+2] + hcnt[3][4*lane+2];
        int c3 = hcnt[0][4*lane+3] + hcnt[1][4*lane+3] + hcnt[2][4*lane+3] + hcnt[3][4*lane+3];
        int suf3 = c3;
        int suf2 = c2 + suf3;
        int suf1 = c1 + suf2;
        int suf0 = c0 + suf1;
        int inc = suf0;                       // inclusive suffix over lane quads
        #pragma unroll
        for (int off = 1; off < 64; off <<= 1) {
            int tmp = __shfl_down(inc, off);
            inc += (lane + off < 64) ? tmp : 0;
        }
        int eAbove = inc - suf0;              // sum over lanes > this lane
        int S0 = suf0 + eAbove, S1 = suf1 + eAbove;
        int S2 = suf2 + eAbove, S3 = suf3 + eAbove;
        int SN0 = S1, SN1 = S2, SN2 = S3, SN3 = eAbove;
        if (S0 >= 256 && SN0 < 256) { ctrl[1] = 4*lane+0; ctrl[2] = 256 - SN0; }
        if (S1 >= 256 && SN1 < 256) { ctrl[1] = 4*lane+1; ctrl[2] = 256 - SN1; }
        if (S2 >= 256 && SN2 < 256) { ctrl[1] = 4*lane+2; ctrl[2] = 256 - SN2; }
        if (S3 >= 256 && SN3 < 256) { ctrl[1] = 4*lane+3; ctrl[2] = 256 - SN3; }
    }
    __syncthreads();
    const int bb = ctrl[1];
    const int r  = ctrl[2];

    // ---- pass 2: re-read (L2-hot). bins>bb: accumulate relu(v-0.2).
    // bin==bb: push monotone u16 key to list.
    float sloc = 0.f;
    #pragma unroll
    for (int q = 0; q < 4; q++) {
        uint4 w = rp4[q * 256 + t];
        unsigned wd[4] = {w.x, w.y, w.z, w.w};
        #pragma unroll
        for (int u = 0; u < 4; u++) {
            unsigned x = wd[u];
            #pragma unroll
            for (int h = 0; h < 2; h++) {
                unsigned bits = (h == 0) ? (x & 0xFFFFu) : (x >> 16);
                float v = bf2f(bits);
                int bin = min(255, max(0, (int)floorf(v * 2.0f) + 128));
                if (bin > bb) {
                    sloc += fmaxf(v - 0.2f, 0.0f);
                } else if (bin == bb) {
                    int idx = (int)atomicAdd((unsigned*)&ctrl[0], 1u);
                    list[idx] = (ushort)(bits ^ ((bits & 0x8000u) ? 0xFFFFu : 0x8000u));
                }
            }
        }
    }
    #pragma unroll
    for (int off = 32; off >= 1; off >>= 1) sloc += __shfl_down(sloc, off);
    if (lane == 0) s_s[wave] = sloc;
    __syncthreads();

    if (wave != 0) return;

    // ---- wave 0: bisect the list (u16 key domain) for the r-th largest.
    const int lc = ctrl[0];                   // == cnt[bb] >= r >= 1
    const int maxit = (lc + 63) >> 6;         // uniform across the wave
    int lo = -1, hi = 65535;                  // cnt(>lo) >= r, cnt(>hi) <= r-1
    for (int it = 0; it < 16; it++) {
        int mid = (lo + hi) >> 1;
        int c = 0;
        for (int j = 0; j < maxit; j++) {
            int i = lane + (j << 6);
            bool p = (i < lc) && ((int)list[i] > mid);
            c += (int)__popcll(__ballot(p));  // wave-uniform count
        }
        if (c >= r) lo = mid; else hi = mid;
    }
    const unsigned kt = (unsigned)hi;         // key of r-th largest (attained)

    float s = 0.f; int cgt = 0;
    for (int j = 0; j < maxit; j++) {
        int i = lane + (j << 6);
        bool valid = (i < lc);
        unsigned kv = valid ? (unsigned)list[i] : 0u;
        bool gt = valid && (kv > kt);
        cgt += (int)__popcll(__ballot(gt));
        if (gt) {
            unsigned bbits = kv ^ ((kv & 0x8000u) ? 0x8000u : 0xFFFFu);
            s += fmaxf(bf2f(bbits) - 0.2f, 0.0f);
        }
    }
    #pragma unroll
    for (int off = 32; off >= 1; off >>= 1) s += __shfl_down(s, off);
    if (lane == 0) {
        unsigned bt = kt ^ ((kt & 0x8000u) ? 0x8000u : 0xFFFFu);
        float vt = bf2f(bt);
        float total = s_s[0] + s_s[1] + s_s[2] + s_s[3] + s
                    + (float)(r - cgt) * fmaxf(vt - 0.2f, 0.0f);
        atomicAdd(out, total * INV_DENOM);
    }
}

extern "C" void kernel_launch(void* const* d_in, const int* in_sizes, int n_in,
                              void* d_out, int out_size, void* d_ws, size_t ws_size,
                              hipStream_t stream) {
    const float* wkp1  = (const float*)d_in[1];
    const float* kp2   = (const float*)d_in[2];
    const float* kp1d  = (const float*)d_in[3];
    const float* kp2d  = (const float*)d_in[4];
    const float* desc2 = (const float*)d_in[5];
    float* out = (float*)d_out;

    ushort* Abf = (ushort*)d_ws;                 // 2 MB
    ushort* Bbf = Abf + (size_t)N1 * CDIM;       // 2 MB
    ushort* dots = Bbf + (size_t)N2 * CDIM;      // remainder: desc_dot chunks (bf16)

    size_t desc_bytes = (size_t)(N1 + N2) * CDIM * sizeof(ushort);
    size_t avail = (ws_size > desc_bytes) ? (ws_size - desc_bytes) : 0;
    long rows_chunk = (long)(avail / ((size_t)N2 * sizeof(ushort)));
    rows_chunk = (rows_chunk / 128) * 128;
    if (rows_chunk > N1) rows_chunk = N1;
    if (rows_chunk < 128) rows_chunk = 128;      // requires ws >= ~6 MB

    hipMemsetAsync(d_out, 0, sizeof(float), stream);

    int n4 = N1 * CDIM / 4;
    cvt_kernel<<<(n4 + 255) / 256, 256, 0, stream>>>(kp1d, Abf, n4);
    cvt_kernel<<<(n4 + 255) / 256, 256, 0, stream>>>(kp2d, Bbf, n4);

    pos_kernel<<<N1, 128, 0, stream>>>(wkp1, kp1d, desc2, out);

    for (int r0 = 0; r0 < N1; r0 += (int)rows_chunk) {
        int rows = (int)((N1 - r0 < rows_chunk) ? (N1 - r0) : rows_chunk);
        dim3 grid(N2 / 128, rows / 128);
        gemm_kernel<<<grid, 256, 0, stream>>>(Abf, Bbf, wkp1, kp2, dots, r0);
        select_kernel<<<rows, 256, 0, stream>>>(dots, out);
    }
}